// Round 1
// baseline (921.183 us; speedup 1.0000x reference)
//
#include <hip/hip_runtime.h>
#include <hip/hip_bf16.h>

// SpatialGather: context[k,c] = sum_n softmax_k(logits[:,n]) * feats[c,n] / colsum[k]
// feats: (C=512, N=262144) fp32, logits: (K=150, N) fp32, out: (150, 512) fp32.
// Memory floor 669 MB => ~106 us @ 6.3 TB/s. bf16 MFMA makes compute negligible.

#define N_PIX (512 * 512)            // 262144
#define K_CLS 150
#define C_DIM 512
#define NBLK 256
#define PIX_PER_BLK (N_PIX / NBLK)   // 1024
#define CHUNK 64
#define NCHUNK (PIX_PER_BLK / CHUNK) // 16

typedef short short8 __attribute__((ext_vector_type(8)));
typedef float floatx4 __attribute__((ext_vector_type(4)));

__device__ __forceinline__ unsigned short f2bf(float x) {
  // round-to-nearest-even f32 -> bf16
  unsigned u = __builtin_bit_cast(unsigned, x);
  u += 0x7FFFu + ((u >> 16) & 1u);
  return (unsigned short)(u >> 16);
}

__device__ __forceinline__ void async_ld4(const float* g, float* l) {
  __builtin_amdgcn_global_load_lds(
      (const __attribute__((address_space(1))) void*)g,
      (__attribute__((address_space(3))) void*)l, 4, 0, 0);
}

__global__ __launch_bounds__(512) void sg_main(
    const float* __restrict__ feats, const float* __restrict__ logits,
    float* __restrict__ ctx, float* __restrict__ colsum_g)
{
  // LDS: 76.8 KB raw-logits ping-pong + 20.5 KB A-tile + reduce scratch (~100 KB)
  __shared__ float lraw[2][K_CLS][CHUNK];
  __shared__ unsigned short atile[20 * 64 * 8];   // 10 row-groups x 2 ksteps, frag-contiguous
  __shared__ float part[8][64];
  __shared__ float colsum_lds[K_CLS];

  const int tid  = threadIdx.x;
  const int w    = tid >> 6;        // wave id 0..7
  const int lane = tid & 63;
  const int quad = lane >> 4;
  const int l15  = lane & 15;
  const int nbase = blockIdx.x * PIX_PER_BLK;

  // zero A-tile once (rows 150..159 stay zero forever)
  for (int i = tid; i < 20 * 64 * 8 / 2; i += 512) ((unsigned*)atile)[i] = 0u;
  if (tid < K_CLS) colsum_lds[tid] = 0.f;

  floatx4 acc[4][10];
#pragma unroll
  for (int j = 0; j < 4; ++j)
#pragma unroll
    for (int rg = 0; rg < 10; ++rg)
      acc[j][rg] = (floatx4){0.f, 0.f, 0.f, 0.f};

  // prefetch chunk 0 logits into lraw[0] (DMA: uniform base + lane*4)
#pragma unroll
  for (int i = 0; i < 19; ++i) {
    const int k = w + 8 * i;
    if (k < K_CLS)
      async_ld4(logits + (size_t)k * N_PIX + nbase + lane, &lraw[0][k][0]);
  }

  for (int ci = 0; ci < NCHUNK; ++ci) {
    __syncthreads();                 // drains DMA prefetch; protects atile/lraw
    const int buf = ci & 1;
    const int n0  = nbase + ci * CHUNK;

    // issue feats loads for k-step 0 (pixels n0 .. n0+31), 4 col-groups per wave
    floatx4 breg[8];
#pragma unroll
    for (int j = 0; j < 4; ++j) {
      const float* bp = feats + (size_t)((w + 8 * j) * 16 + l15) * N_PIX + n0 + quad * 8;
      breg[2 * j]     = *(const floatx4*)bp;
      breg[2 * j + 1] = *(const floatx4*)(bp + 4);
    }

    // phase 1a: softmax denominator for this lane's pixel (n0+lane)
    float s_part = 0.f;
#pragma unroll
    for (int i = 0; i < 19; ++i) {
      const int k = w + 8 * i;
      if (k < K_CLS) s_part += __expf(lraw[buf][k][lane]);
    }
    part[w][lane] = s_part;
    __syncthreads();
    float s = 0.f;
#pragma unroll
    for (int ww = 0; ww < 8; ++ww) s += part[ww][lane];
    const float rs = 1.0f / s;       // denom > 0 always; clip is on colsum, in epilogue

    // phase 1b: probs -> bf16 A-tile (MFMA A-fragment layout) + colsum partials
#pragma unroll
    for (int i = 0; i < 19; ++i) {
      const int k = w + 8 * i;
      if (k < K_CLS) {
        const float p = __expf(lraw[buf][k][lane]) * rs;
        const int fid = ((k >> 4) << 1) + (lane >> 5);          // rg*2 + kstep
        const int lin = (k & 15) | (((lane >> 3) & 3) << 4);    // lane-in-fragment
        atile[(fid * 64 + lin) * 8 + (lane & 7)] = f2bf(p);
        float r = p;                                            // reduce over 64 pixels
        r += __shfl_xor(r, 32);
        r += __shfl_xor(r, 16);
        r += __shfl_xor(r, 8);
        r += __shfl_xor(r, 4);
        r += __shfl_xor(r, 2);
        r += __shfl_xor(r, 1);
        if (lane == 0) colsum_lds[k] += r;   // row k owned exclusively by wave w
      }
    }
    __syncthreads();                 // A-tile ready (also drains breg ks0)

    // convert feats k-step 0 to bf16 fragments
    short8 bfrag[4];
#pragma unroll
    for (int j = 0; j < 4; ++j) {
      floatx4 lo = breg[2 * j], hi = breg[2 * j + 1];
      short8 f;
      f[0] = f2bf(lo[0]); f[1] = f2bf(lo[1]); f[2] = f2bf(lo[2]); f[3] = f2bf(lo[3]);
      f[4] = f2bf(hi[0]); f[5] = f2bf(hi[1]); f[6] = f2bf(hi[2]); f[7] = f2bf(hi[3]);
      bfrag[j] = f;
    }

    // issue feats loads for k-step 1 (pixels n0+32 .. n0+63)
#pragma unroll
    for (int j = 0; j < 4; ++j) {
      const float* bp = feats + (size_t)((w + 8 * j) * 16 + l15) * N_PIX + n0 + 32 + quad * 8;
      breg[2 * j]     = *(const floatx4*)bp;
      breg[2 * j + 1] = *(const floatx4*)(bp + 4);
    }

    // prefetch next chunk's logits AFTER the ks1 loads, so the ks1 vmcnt wait
    // does not have to drain the DMA (vmcnt drains oldest-first)
    if (ci + 1 < NCHUNK) {
#pragma unroll
      for (int i = 0; i < 19; ++i) {
        const int k = w + 8 * i;
        if (k < K_CLS)
          async_ld4(logits + (size_t)k * N_PIX + n0 + CHUNK + lane, &lraw[buf ^ 1][k][0]);
      }
    }

    // MFMA k-step 0
#pragma unroll
    for (int rg = 0; rg < 10; ++rg) {
      short8 afrag = *(const short8*)&atile[((rg * 2 + 0) * 64 + lane) * 8];
#pragma unroll
      for (int j = 0; j < 4; ++j)
        acc[j][rg] = __builtin_amdgcn_mfma_f32_16x16x32_bf16(afrag, bfrag[j], acc[j][rg], 0, 0, 0);
    }

    // convert feats k-step 1
#pragma unroll
    for (int j = 0; j < 4; ++j) {
      floatx4 lo = breg[2 * j], hi = breg[2 * j + 1];
      short8 f;
      f[0] = f2bf(lo[0]); f[1] = f2bf(lo[1]); f[2] = f2bf(lo[2]); f[3] = f2bf(lo[3]);
      f[4] = f2bf(hi[0]); f[5] = f2bf(hi[1]); f[6] = f2bf(hi[2]); f[7] = f2bf(hi[3]);
      bfrag[j] = f;
    }

    // MFMA k-step 1
#pragma unroll
    for (int rg = 0; rg < 10; ++rg) {
      short8 afrag = *(const short8*)&atile[((rg * 2 + 1) * 64 + lane) * 8];
#pragma unroll
      for (int j = 0; j < 4; ++j)
        acc[j][rg] = __builtin_amdgcn_mfma_f32_16x16x32_bf16(afrag, bfrag[j], acc[j][rg], 0, 0, 0);
    }
  }

  // flush partial context tile (C/D layout: col = lane&15, row = quad*4 + r)
#pragma unroll
  for (int j = 0; j < 4; ++j) {
    const int c = ((w + 8 * j) << 4) + l15;
#pragma unroll
    for (int rg = 0; rg < 10; ++rg) {
#pragma unroll
      for (int r = 0; r < 4; ++r) {
        const int row = rg * 16 + quad * 4 + r;
        if (row < K_CLS) atomicAdd(&ctx[row * C_DIM + c], acc[j][rg][r]);
      }
    }
  }
  __syncthreads();
  if (tid < K_CLS) atomicAdd(&colsum_g[tid], colsum_lds[tid]);
}

__global__ void sg_epi(const float* __restrict__ ctx, const float* __restrict__ colsum,
                       float* __restrict__ out)
{
  const int idx = blockIdx.x * 256 + threadIdx.x;
  if (idx < K_CLS * C_DIM) {
    const float d = fmaxf(colsum[idx >> 9], 1e-6f);
    out[idx] = ctx[idx] / d;
  }
}

extern "C" void kernel_launch(void* const* d_in, const int* in_sizes, int n_in,
                              void* d_out, int out_size, void* d_ws, size_t ws_size,
                              hipStream_t stream)
{
  const float* feats  = (const float*)d_in[0];   // (512, 262144) fp32
  const float* logits = (const float*)d_in[1];   // (150, 262144) fp32
  float* ctx    = (float*)d_ws;                  // 150*512 fp32 accumulator
  float* colsum = ctx + K_CLS * C_DIM;           // 150 fp32
  hipMemsetAsync(d_ws, 0, (K_CLS * C_DIM + K_CLS) * sizeof(float), stream);
  sg_main<<<dim3(NBLK), dim3(512), 0, stream>>>(feats, logits, ctx, colsum);
  sg_epi<<<dim3((K_CLS * C_DIM + 255) / 256), dim3(256), 0, stream>>>(ctx, colsum, (float*)d_out);
}